// Round 1
// baseline (553.295 us; speedup 1.0000x reference)
//
#include <hip/hip_runtime.h>
#include <math.h>

#define EMBED 768
#define FFN_D 3072
#define TSEQ 4096
#define NHEAD 12
#define DHEAD 64
#define CQKV 2304   // 3*EMBED

typedef _Float16 f16;
typedef __attribute__((ext_vector_type(8))) _Float16 f16x8;
typedef __attribute__((ext_vector_type(4))) float f32x4;

// ---------------- transpose + fp32->fp16 convert: W[din][dout] -> WT[dout][din]
__global__ __launch_bounds__(256) void tconv_kernel(const float* __restrict__ W,
                                                    f16* __restrict__ WT,
                                                    int din, int dout) {
    __shared__ float tile[32][33];
    const int j0 = blockIdx.x * 32;   // dout
    const int i0 = blockIdx.y * 32;   // din
    const int tx = threadIdx.x & 31;
    const int ty = threadIdx.x >> 5;  // 0..7
#pragma unroll
    for (int rr = ty; rr < 32; rr += 8)
        tile[rr][tx] = W[(size_t)(i0 + rr) * dout + j0 + tx];
    __syncthreads();
#pragma unroll
    for (int rr = ty; rr < 32; rr += 8)
        WT[(size_t)(j0 + rr) * din + i0 + tx] = (f16)tile[tx][rr];
}

// ---------------- concat 3 bias vectors of 768 into [2304]
__global__ void concat3_kernel(const float* __restrict__ a, const float* __restrict__ b,
                               const float* __restrict__ c, float* __restrict__ o) {
    int i = blockIdx.x * 256 + threadIdx.x;
    if (i < 768) o[i] = a[i];
    else if (i < 1536) o[i] = b[i - 768];
    else if (i < 2304) o[i] = c[i - 1536];
}

// ---------------- LayerNorm row kernel (768 wide), writes f32 + f16
__global__ __launch_bounds__(256) void ln_kernel(const float* __restrict__ x,
                                                 const float* __restrict__ g,
                                                 const float* __restrict__ b,
                                                 float* __restrict__ hf,
                                                 f16* __restrict__ hh) {
    const int row = blockIdx.x;
    const float* xr = x + (size_t)row * EMBED;
    const int t = threadIdx.x;
    float v0 = xr[t], v1 = xr[t + 256], v2 = xr[t + 512];
    float s = v0 + v1 + v2;
#pragma unroll
    for (int m = 1; m < 64; m <<= 1) s += __shfl_xor(s, m);
    __shared__ float red[4], red2[4];
    const int wid = t >> 6, lane = t & 63;
    if (lane == 0) red[wid] = s;
    __syncthreads();
    float mean = (red[0] + red[1] + red[2] + red[3]) * (1.0f / 768.0f);
    float d0 = v0 - mean, d1 = v1 - mean, d2 = v2 - mean;
    float ss = d0 * d0 + d1 * d1 + d2 * d2;
#pragma unroll
    for (int m = 1; m < 64; m <<= 1) ss += __shfl_xor(ss, m);
    if (lane == 0) red2[wid] = ss;
    __syncthreads();
    float inv = rsqrtf((red2[0] + red2[1] + red2[2] + red2[3]) * (1.0f / 768.0f) + 1e-5f);
    float o0 = d0 * inv * g[t] + b[t];
    float o1 = d1 * inv * g[t + 256] + b[t + 256];
    float o2 = d2 * inv * g[t + 512] + b[t + 512];
    size_t base = (size_t)row * EMBED;
    hf[base + t] = o0; hf[base + t + 256] = o1; hf[base + t + 512] = o2;
    hh[base + t] = (f16)o0; hh[base + t + 256] = (f16)o1; hh[base + t + 512] = (f16)o2;
}

// ---------------- GEMM: C[M][N] = A[M][K] * BT[N][K]^T + bias
// EPI 0: out fp16          EPI 1: out fp32 = acc+bias+res   EPI 2: out fp16 = gelu(acc+bias)
template <int EPI>
__global__ __launch_bounds__(256) void gemm_kernel(const f16* __restrict__ A,
                                                   const f16* __restrict__ BT,
                                                   const float* __restrict__ bias,
                                                   const float* __restrict__ res,
                                                   float* __restrict__ outf,
                                                   f16* __restrict__ outh,
                                                   int M, int N, int K) {
    __shared__ __align__(16) f16 As[128][40];   // 80B row stride: 16B-aligned, 2-way bank alias (free)
    __shared__ __align__(16) f16 Bs[128][40];
    const int t = threadIdx.x;
    const int m0 = blockIdx.y * 128;
    const int n0 = blockIdx.x * 128;
    const int sr = t >> 2;            // 0..63
    const int sc = (t & 3) * 8;       // 0,8,16,24
    const int wid = t >> 6;
    const int lane = t & 63;
    const int wm = (wid >> 1) * 64;
    const int wn = (wid & 1) * 64;
    const int lr = lane & 15;
    const int lk = (lane >> 4) * 8;

    f32x4 zero = {0.f, 0.f, 0.f, 0.f};
    f32x4 acc[4][4];
#pragma unroll
    for (int i = 0; i < 4; i++)
#pragma unroll
        for (int j = 0; j < 4; j++) acc[i][j] = zero;

    const f16* Ap = A + (size_t)(m0 + sr) * K + sc;
    const f16* Bp = BT + (size_t)(n0 + sr) * K + sc;

    for (int k0 = 0; k0 < K; k0 += 32) {
        __syncthreads();
        *(int4*)&As[sr][sc]      = *(const int4*)(Ap + k0);
        *(int4*)&As[sr + 64][sc] = *(const int4*)(Ap + (size_t)64 * K + k0);
        *(int4*)&Bs[sr][sc]      = *(const int4*)(Bp + k0);
        *(int4*)&Bs[sr + 64][sc] = *(const int4*)(Bp + (size_t)64 * K + k0);
        __syncthreads();
        f16x8 af[4], bf[4];
#pragma unroll
        for (int i = 0; i < 4; i++) af[i] = *(const f16x8*)&As[wm + i * 16 + lr][lk];
#pragma unroll
        for (int j = 0; j < 4; j++) bf[j] = *(const f16x8*)&Bs[wn + j * 16 + lr][lk];
#pragma unroll
        for (int i = 0; i < 4; i++)
#pragma unroll
            for (int j = 0; j < 4; j++)
                acc[i][j] = __builtin_amdgcn_mfma_f32_16x16x32_f16(af[i], bf[j], acc[i][j], 0, 0, 0);
    }

    const int q4 = (lane >> 4) * 4;
#pragma unroll
    for (int i = 0; i < 4; i++) {
        const int row = m0 + wm + i * 16 + q4;
#pragma unroll
        for (int j = 0; j < 4; j++) {
            const int col = n0 + wn + j * 16 + lr;
            const float bv = bias[col];
#pragma unroll
            for (int r = 0; r < 4; r++) {
                float v = acc[i][j][r] + bv;
                size_t idx = (size_t)(row + r) * N + col;
                if (EPI == 0) {
                    outh[idx] = (f16)v;
                } else if (EPI == 1) {
                    outf[idx] = v + res[idx];
                } else {
                    float gl = 0.5f * v * (1.0f + erff(v * 0.70710678118654752f));
                    outh[idx] = (f16)gl;
                }
            }
        }
    }
}

// ---------------- flash-style causal attention
// qkv: [TSEQ][2304] fp16 (q|k|v sections). ctx: [TSEQ][768] fp16.
__global__ __launch_bounds__(256) void attn_kernel(const f16* __restrict__ qkv,
                                                   f16* __restrict__ ctx) {
    __shared__ __align__(16) f16 Qs[64][72];
    __shared__ __align__(16) f16 Ks[64][72];
    __shared__ __align__(16) f16 Vt[64][72];       // [d][key]
    __shared__ __align__(16) f16 Ps[4][16][72];    // per-wave P tile
    const int qb = blockIdx.x;          // 0..63
    const int h  = blockIdx.y;          // 0..11
    const int q0 = qb * 64;
    const int t = threadIdx.x;
    const int wid = t >> 6;
    const int lane = t & 63;
    const int lr = lane & 15;
    const int quad = lane >> 4;
    const int lk = quad * 8;
    const int sr = t >> 2;              // 0..63
    const int sc = (t & 3) * 8;         // 0,8,16,24

    // stage Q tile (64 rows x 64 d)
    {
        const f16* qrow = qkv + (size_t)(q0 + sr) * CQKV + h * DHEAD;
        *(int4*)&Qs[sr][sc]      = *(const int4*)(qrow + sc);
        *(int4*)&Qs[sr][sc + 32] = *(const int4*)(qrow + sc + 32);
    }

    float m_i[4], l_i[4];
    f32x4 zero = {0.f, 0.f, 0.f, 0.f};
    f32x4 o[4];
#pragma unroll
    for (int r = 0; r < 4; r++) { m_i[r] = -INFINITY; l_i[r] = 0.f; }
#pragma unroll
    for (int j = 0; j < 4; j++) o[j] = zero;

    for (int kb = 0; kb <= qb; ++kb) {
        __syncthreads();   // previous iteration's reads of Ks/Vt (and Q staging) done
        {
            const f16* krow = qkv + (size_t)(kb * 64 + sr) * CQKV + EMBED + h * DHEAD;
            *(int4*)&Ks[sr][sc]      = *(const int4*)(krow + sc);
            *(int4*)&Ks[sr][sc + 32] = *(const int4*)(krow + sc + 32);
            const f16* vrow = qkv + (size_t)(kb * 64 + sr) * CQKV + 2 * EMBED + h * DHEAD;
#pragma unroll
            for (int half = 0; half < 2; ++half) {
                int4 vv = *(const int4*)(vrow + sc + half * 32);
                const f16* ve = (const f16*)&vv;
#pragma unroll
                for (int e = 0; e < 8; e++) Vt[sc + half * 32 + e][sr] = ve[e];
            }
        }
        __syncthreads();

        // S = Q K^T  (per wave: 16 q-rows x 64 keys)
        f32x4 s[4];
#pragma unroll
        for (int j = 0; j < 4; j++) s[j] = zero;
#pragma unroll
        for (int ks = 0; ks < 2; ++ks) {
            f16x8 aq = *(const f16x8*)&Qs[wid * 16 + lr][ks * 32 + lk];
#pragma unroll
            for (int j = 0; j < 4; j++) {
                f16x8 bk = *(const f16x8*)&Ks[j * 16 + lr][ks * 32 + lk];
                s[j] = __builtin_amdgcn_mfma_f32_16x16x32_f16(aq, bk, s[j], 0, 0, 0);
            }
        }
        // scale + causal mask (diag tile only)
#pragma unroll
        for (int j = 0; j < 4; j++)
#pragma unroll
            for (int r = 0; r < 4; r++) {
                float sv = s[j][r] * 0.125f;
                if (kb == qb && (j * 16 + lr) > (wid * 16 + quad * 4 + r)) sv = -INFINITY;
                s[j][r] = sv;
            }
        // row max over 64 keys (4 tiles in-reg + 16-lane shuffle)
        float mt[4];
#pragma unroll
        for (int r = 0; r < 4; r++) {
            float v = fmaxf(fmaxf(s[0][r], s[1][r]), fmaxf(s[2][r], s[3][r]));
            v = fmaxf(v, __shfl_xor(v, 1));
            v = fmaxf(v, __shfl_xor(v, 2));
            v = fmaxf(v, __shfl_xor(v, 4));
            v = fmaxf(v, __shfl_xor(v, 8));
            mt[r] = v;
        }
        float al[4];
#pragma unroll
        for (int r = 0; r < 4; r++) {
            float mn = fmaxf(m_i[r], mt[r]);
            al[r] = expf(m_i[r] - mn);   // expf(-inf)=0 on first visit
            m_i[r] = mn;
        }
        // P = exp(S - m), row sums
        float rs[4] = {0.f, 0.f, 0.f, 0.f};
        f16 pv[4][4];
#pragma unroll
        for (int j = 0; j < 4; j++)
#pragma unroll
            for (int r = 0; r < 4; r++) {
                float p = expf(s[j][r] - m_i[r]);
                rs[r] += p;
                pv[j][r] = (f16)p;
            }
#pragma unroll
        for (int r = 0; r < 4; r++) {
            float v = rs[r];
            v += __shfl_xor(v, 1);
            v += __shfl_xor(v, 2);
            v += __shfl_xor(v, 4);
            v += __shfl_xor(v, 8);
            l_i[r] = l_i[r] * al[r] + v;
        }
        // write P (C-layout -> LDS -> A-layout)
#pragma unroll
        for (int j = 0; j < 4; j++)
#pragma unroll
            for (int r = 0; r < 4; r++)
                Ps[wid][quad * 4 + r][j * 16 + lr] = pv[j][r];
        __syncthreads();
        // rescale O, then O += P @ V
#pragma unroll
        for (int j = 0; j < 4; j++)
#pragma unroll
            for (int r = 0; r < 4; r++) o[j][r] *= al[r];
#pragma unroll
        for (int ks = 0; ks < 2; ++ks) {
            f16x8 ap = *(const f16x8*)&Ps[wid][lr][ks * 32 + lk];
#pragma unroll
            for (int j = 0; j < 4; j++) {
                f16x8 bv = *(const f16x8*)&Vt[j * 16 + lr][ks * 32 + lk];
                o[j] = __builtin_amdgcn_mfma_f32_16x16x32_f16(ap, bv, o[j], 0, 0, 0);
            }
        }
    }

    // write ctx
#pragma unroll
    for (int j = 0; j < 4; j++)
#pragma unroll
        for (int r = 0; r < 4; r++) {
            int row = q0 + wid * 16 + quad * 4 + r;
            int col = h * DHEAD + j * 16 + lr;
            ctx[(size_t)row * EMBED + col] = (f16)(o[j][r] / l_i[r]);
        }
}

extern "C" void kernel_launch(void* const* d_in, const int* in_sizes, int n_in,
                              void* d_out, int out_size, void* d_ws, size_t ws_size,
                              hipStream_t stream) {
    const float* x     = (const float*)d_in[0];
    const float* Wq    = (const float*)d_in[1];
    const float* bq    = (const float*)d_in[2];
    const float* Wk    = (const float*)d_in[3];
    const float* bk    = (const float*)d_in[4];
    const float* Wv    = (const float*)d_in[5];
    const float* bv    = (const float*)d_in[6];
    const float* Wo    = (const float*)d_in[7];
    const float* bo    = (const float*)d_in[8];
    const float* ln1_g = (const float*)d_in[9];
    const float* ln1_b = (const float*)d_in[10];
    const float* ln2_g = (const float*)d_in[11];
    const float* ln2_b = (const float*)d_in[12];
    const float* W1    = (const float*)d_in[13];
    const float* b1    = (const float*)d_in[14];
    const float* W2    = (const float*)d_in[15];
    const float* b2    = (const float*)d_in[16];

    char* p = (char*)d_ws;
    auto alloc = [&](size_t bytes) -> void* {
        void* r = (void*)p;
        p += (bytes + 255) & ~(size_t)255;
        return r;
    };
    f16*   WqkvT = (f16*)alloc((size_t)CQKV * EMBED * 2);   // [2304][768]
    f16*   WoT   = (f16*)alloc((size_t)EMBED * EMBED * 2);  // [768][768]
    f16*   W1T   = (f16*)alloc((size_t)FFN_D * EMBED * 2);  // [3072][768]
    f16*   W2T   = (f16*)alloc((size_t)EMBED * FFN_D * 2);  // [768][3072]
    float* bqkv  = (float*)alloc((size_t)CQKV * 4);
    float* hf    = (float*)alloc((size_t)TSEQ * EMBED * 4);
    f16*   hh    = (f16*)alloc((size_t)TSEQ * EMBED * 2);
    f16*   qkv   = (f16*)alloc((size_t)TSEQ * CQKV * 2);
    f16*   ctx   = (f16*)alloc((size_t)TSEQ * EMBED * 2);
    float* x2    = (float*)alloc((size_t)TSEQ * EMBED * 4);
    float* h2f   = (float*)alloc((size_t)TSEQ * EMBED * 4);
    f16*   h2h   = (f16*)alloc((size_t)TSEQ * EMBED * 2);
    f16*   m1    = (f16*)alloc((size_t)TSEQ * FFN_D * 2);

    dim3 blk(256);
    // weight transposes (fp32 -> fp16, [din][dout] -> [dout][din])
    tconv_kernel<<<dim3(EMBED / 32, EMBED / 32), blk, 0, stream>>>(Wq, WqkvT, EMBED, EMBED);
    tconv_kernel<<<dim3(EMBED / 32, EMBED / 32), blk, 0, stream>>>(Wk, WqkvT + (size_t)EMBED * EMBED, EMBED, EMBED);
    tconv_kernel<<<dim3(EMBED / 32, EMBED / 32), blk, 0, stream>>>(Wv, WqkvT + (size_t)2 * EMBED * EMBED, EMBED, EMBED);
    tconv_kernel<<<dim3(EMBED / 32, EMBED / 32), blk, 0, stream>>>(Wo, WoT, EMBED, EMBED);
    tconv_kernel<<<dim3(FFN_D / 32, EMBED / 32), blk, 0, stream>>>(W1, W1T, EMBED, FFN_D);
    tconv_kernel<<<dim3(EMBED / 32, FFN_D / 32), blk, 0, stream>>>(W2, W2T, FFN_D, EMBED);
    concat3_kernel<<<dim3(9), blk, 0, stream>>>(bq, bk, bv, bqkv);

    // LN1
    ln_kernel<<<dim3(TSEQ), blk, 0, stream>>>(x, ln1_g, ln1_b, hf, hh);
    // QKV fused GEMM: [4096][768] x [2304][768]^T -> fp16 [4096][2304]
    gemm_kernel<0><<<dim3(CQKV / 128, TSEQ / 128), blk, 0, stream>>>(
        hh, WqkvT, bqkv, nullptr, nullptr, qkv, TSEQ, CQKV, EMBED);
    // attention
    attn_kernel<<<dim3(TSEQ / 64, NHEAD), blk, 0, stream>>>(qkv, ctx);
    // Wo GEMM + residual(h): x2 = ctx@Wo + bo + h
    gemm_kernel<1><<<dim3(EMBED / 128, TSEQ / 128), blk, 0, stream>>>(
        ctx, WoT, bo, hf, x2, nullptr, TSEQ, EMBED, EMBED);
    // LN2
    ln_kernel<<<dim3(TSEQ), blk, 0, stream>>>(x2, ln2_g, ln2_b, h2f, h2h);
    // FFN1 + gelu: m1 = gelu(h2@W1 + b1) fp16 [4096][3072]
    gemm_kernel<2><<<dim3(FFN_D / 128, TSEQ / 128), blk, 0, stream>>>(
        h2h, W1T, b1, nullptr, nullptr, m1, TSEQ, FFN_D, EMBED);
    // FFN2 + residual(h2): out = m1@W2 + b2 + h2  (fp32 to d_out)
    gemm_kernel<1><<<dim3(EMBED / 128, TSEQ / 128), blk, 0, stream>>>(
        m1, W2T, b2, h2f, (float*)d_out, nullptr, TSEQ, EMBED, FFN_D);
}

// Round 2
// 504.805 us; speedup vs baseline: 1.0961x; 1.0961x over previous
//
#include <hip/hip_runtime.h>
#include <math.h>

#define EMBED 768
#define FFN_D 3072
#define TSEQ 4096
#define NHEAD 12
#define DHEAD 64
#define CQKV 2304   // 3*EMBED

typedef _Float16 f16;
typedef __attribute__((ext_vector_type(8))) _Float16 f16x8;
typedef __attribute__((ext_vector_type(4))) float f32x4;

// ---------------- transpose + fp32->fp16 convert: W[din][dout] -> WT[dout][din]
__global__ __launch_bounds__(256) void tconv_kernel(const float* __restrict__ W,
                                                    f16* __restrict__ WT,
                                                    int din, int dout) {
    __shared__ float tile[32][33];
    const int j0 = blockIdx.x * 32;   // dout
    const int i0 = blockIdx.y * 32;   // din
    const int tx = threadIdx.x & 31;
    const int ty = threadIdx.x >> 5;  // 0..7
#pragma unroll
    for (int rr = ty; rr < 32; rr += 8)
        tile[rr][tx] = W[(size_t)(i0 + rr) * dout + j0 + tx];
    __syncthreads();
#pragma unroll
    for (int rr = ty; rr < 32; rr += 8)
        WT[(size_t)(j0 + rr) * din + i0 + tx] = (f16)tile[tx][rr];
}

// ---------------- f16 transpose of the V section of qkv -> vT[h*64+d][t]
__global__ __launch_bounds__(256) void vtrans_kernel(const f16* __restrict__ qkv,
                                                     f16* __restrict__ vT) {
    __shared__ f16 tile[32][34];
    const int t0 = blockIdx.x * 32;   // seq
    const int c0 = blockIdx.y * 32;   // channel 0..767
    const int tx = threadIdx.x & 31;
    const int ty = threadIdx.x >> 5;
#pragma unroll
    for (int rr = ty; rr < 32; rr += 8)
        tile[rr][tx] = qkv[(size_t)(t0 + rr) * CQKV + 2 * EMBED + c0 + tx];
    __syncthreads();
#pragma unroll
    for (int rr = ty; rr < 32; rr += 8)
        vT[(size_t)(c0 + rr) * TSEQ + t0 + tx] = tile[tx][rr];
}

// ---------------- concat 3 bias vectors of 768 into [2304]
__global__ void concat3_kernel(const float* __restrict__ a, const float* __restrict__ b,
                               const float* __restrict__ c, float* __restrict__ o) {
    int i = blockIdx.x * 256 + threadIdx.x;
    if (i < 768) o[i] = a[i];
    else if (i < 1536) o[i] = b[i - 768];
    else if (i < 2304) o[i] = c[i - 1536];
}

// ---------------- LayerNorm row kernel (768 wide), writes f32 + f16
__global__ __launch_bounds__(256) void ln_kernel(const float* __restrict__ x,
                                                 const float* __restrict__ g,
                                                 const float* __restrict__ b,
                                                 float* __restrict__ hf,
                                                 f16* __restrict__ hh) {
    const int row = blockIdx.x;
    const float* xr = x + (size_t)row * EMBED;
    const int t = threadIdx.x;
    float v0 = xr[t], v1 = xr[t + 256], v2 = xr[t + 512];
    float s = v0 + v1 + v2;
#pragma unroll
    for (int m = 1; m < 64; m <<= 1) s += __shfl_xor(s, m);
    __shared__ float red[4], red2[4];
    const int wid = t >> 6, lane = t & 63;
    if (lane == 0) red[wid] = s;
    __syncthreads();
    float mean = (red[0] + red[1] + red[2] + red[3]) * (1.0f / 768.0f);
    float d0 = v0 - mean, d1 = v1 - mean, d2 = v2 - mean;
    float ss = d0 * d0 + d1 * d1 + d2 * d2;
#pragma unroll
    for (int m = 1; m < 64; m <<= 1) ss += __shfl_xor(ss, m);
    if (lane == 0) red2[wid] = ss;
    __syncthreads();
    float inv = rsqrtf((red2[0] + red2[1] + red2[2] + red2[3]) * (1.0f / 768.0f) + 1e-5f);
    float o0 = d0 * inv * g[t] + b[t];
    float o1 = d1 * inv * g[t + 256] + b[t + 256];
    float o2 = d2 * inv * g[t + 512] + b[t + 512];
    size_t base = (size_t)row * EMBED;
    hf[base + t] = o0; hf[base + t + 256] = o1; hf[base + t + 512] = o2;
    hh[base + t] = (f16)o0; hh[base + t + 256] = (f16)o1; hh[base + t + 512] = (f16)o2;
}

// ---------------- GEMM: C[M][N] = A[M][K] * BT[N][K]^T + bias
// EPI 0: out fp16          EPI 1: out fp32 = acc+bias+res   EPI 2: out fp16 = gelu(acc+bias)
template <int EPI>
__global__ __launch_bounds__(256) void gemm_kernel(const f16* __restrict__ A,
                                                   const f16* __restrict__ BT,
                                                   const float* __restrict__ bias,
                                                   const float* __restrict__ res,
                                                   float* __restrict__ outf,
                                                   f16* __restrict__ outh,
                                                   int M, int N, int K) {
    __shared__ __align__(16) f16 As[128][40];
    __shared__ __align__(16) f16 Bs[128][40];
    const int t = threadIdx.x;
    const int m0 = blockIdx.y * 128;
    const int n0 = blockIdx.x * 128;
    const int sr = t >> 2;            // 0..63
    const int sc = (t & 3) * 8;       // 0,8,16,24
    const int wid = t >> 6;
    const int lane = t & 63;
    const int wm = (wid >> 1) * 64;
    const int wn = (wid & 1) * 64;
    const int lr = lane & 15;
    const int lk = (lane >> 4) * 8;

    f32x4 zero = {0.f, 0.f, 0.f, 0.f};
    f32x4 acc[4][4];
#pragma unroll
    for (int i = 0; i < 4; i++)
#pragma unroll
        for (int j = 0; j < 4; j++) acc[i][j] = zero;

    const f16* Ap = A + (size_t)(m0 + sr) * K + sc;
    const f16* Bp = BT + (size_t)(n0 + sr) * K + sc;

    for (int k0 = 0; k0 < K; k0 += 32) {
        __syncthreads();
        *(int4*)&As[sr][sc]      = *(const int4*)(Ap + k0);
        *(int4*)&As[sr + 64][sc] = *(const int4*)(Ap + (size_t)64 * K + k0);
        *(int4*)&Bs[sr][sc]      = *(const int4*)(Bp + k0);
        *(int4*)&Bs[sr + 64][sc] = *(const int4*)(Bp + (size_t)64 * K + k0);
        __syncthreads();
        f16x8 af[4], bf[4];
#pragma unroll
        for (int i = 0; i < 4; i++) af[i] = *(const f16x8*)&As[wm + i * 16 + lr][lk];
#pragma unroll
        for (int j = 0; j < 4; j++) bf[j] = *(const f16x8*)&Bs[wn + j * 16 + lr][lk];
#pragma unroll
        for (int i = 0; i < 4; i++)
#pragma unroll
            for (int j = 0; j < 4; j++)
                acc[i][j] = __builtin_amdgcn_mfma_f32_16x16x32_f16(af[i], bf[j], acc[i][j], 0, 0, 0);
    }

    const int q4 = (lane >> 4) * 4;
#pragma unroll
    for (int i = 0; i < 4; i++) {
        const int row = m0 + wm + i * 16 + q4;
#pragma unroll
        for (int j = 0; j < 4; j++) {
            const int col = n0 + wn + j * 16 + lr;
            const float bv = bias[col];
#pragma unroll
            for (int r = 0; r < 4; r++) {
                float v = acc[i][j][r] + bv;
                size_t idx = (size_t)(row + r) * N + col;
                if (EPI == 0) {
                    outh[idx] = (f16)v;
                } else if (EPI == 1) {
                    outf[idx] = v + res[idx];
                } else {
                    float gl = 0.5f * v * (1.0f + erff(v * 0.70710678118654752f));
                    outh[idx] = (f16)gl;
                }
            }
        }
    }
}

// ---------------- flash-style causal attention, 128-row Q tile
// qkv: [TSEQ][2304] fp16 (q|k sections used). vT: [768][TSEQ] fp16. ctx: [TSEQ][768] fp16.
__global__ __launch_bounds__(256) void attn_kernel(const f16* __restrict__ qkv,
                                                   const f16* __restrict__ vT,
                                                   f16* __restrict__ ctx) {
    __shared__ __align__(16) f16 Qs[128][72];
    __shared__ __align__(16) f16 Ks[64][72];
    __shared__ __align__(16) f16 Vt[64][72];      // [d][key]
    __shared__ __align__(16) f16 Ps[4][32][72];   // per-wave P tile (wave-local, no barrier)
    const int h  = blockIdx.x;                    // 0..11
    const int qb = (gridDim.y - 1) - blockIdx.y;  // longest blocks dispatched first
    const int q0 = qb * 128;
    const int t = threadIdx.x;
    const int wid = t >> 6;
    const int lane = t & 63;
    const int lr = lane & 15;
    const int quad = lane >> 4;
    const int lk = quad * 8;
    const int srow = t >> 3;        // 0..31
    const int scol = (t & 7) * 8;   // 0..56

    // stage Q tile (128 rows x 64 d), coalesced 16B
    {
        const f16* qbase = qkv + (size_t)q0 * CQKV + h * DHEAD;
#pragma unroll
        for (int p = 0; p < 4; p++) {
            int r = p * 32 + srow;
            *(int4*)&Qs[r][scol] = *(const int4*)(qbase + (size_t)r * CQKV + scol);
        }
    }

    float m_i[2][4], l_i[2][4];
    f32x4 zero = {0.f, 0.f, 0.f, 0.f};
    f32x4 o[2][4];
#pragma unroll
    for (int i = 0; i < 2; i++)
#pragma unroll
        for (int r = 0; r < 4; r++) { m_i[i][r] = -INFINITY; l_i[i][r] = 0.f; }
#pragma unroll
    for (int i = 0; i < 2; i++)
#pragma unroll
        for (int j = 0; j < 4; j++) o[i][j] = zero;

    const int wrow0 = q0 + wid * 32;       // first q-row of this wave
    const int nkb = 2 * qb + 2;
    const float sc2 = 0.125f * 1.4426950408889634f;   // 1/sqrt(64) * log2(e)

    for (int kb = 0; kb < nkb; ++kb) {
        const int k0 = kb * 64;
        __syncthreads();   // prior iteration's reads of Ks/Vt done (also covers Q staging)
        {
            const f16* kbase = qkv + (size_t)k0 * CQKV + EMBED + h * DHEAD;
#pragma unroll
            for (int p = 0; p < 2; p++) {
                int r = p * 32 + srow;
                *(int4*)&Ks[r][scol] = *(const int4*)(kbase + (size_t)r * CQKV + scol);
            }
            const f16* vbase = vT + (size_t)h * DHEAD * TSEQ + k0;
#pragma unroll
            for (int p = 0; p < 2; p++) {
                int d = p * 32 + srow;
                *(int4*)&Vt[d][scol] = *(const int4*)(vbase + (size_t)d * TSEQ + scol);
            }
        }
        __syncthreads();

        if (k0 <= wrow0 + 31) {   // wave-uniform: skip fully-masked tiles
            // S = Q K^T : 32 q-rows x 64 keys per wave
            f32x4 s[2][4];
#pragma unroll
            for (int i = 0; i < 2; i++)
#pragma unroll
                for (int j = 0; j < 4; j++) s[i][j] = zero;
#pragma unroll
            for (int i = 0; i < 2; i++)
#pragma unroll
                for (int ks = 0; ks < 2; ks++) {
                    f16x8 aq = *(const f16x8*)&Qs[wid * 32 + i * 16 + lr][ks * 32 + lk];
#pragma unroll
                    for (int j = 0; j < 4; j++) {
                        f16x8 bk = *(const f16x8*)&Ks[j * 16 + lr][ks * 32 + lk];
                        s[i][j] = __builtin_amdgcn_mfma_f32_16x16x32_f16(aq, bk, s[i][j], 0, 0, 0);
                    }
                }
            // scale into log2 domain (+ causal mask only on boundary tiles)
            if (k0 + 63 > wrow0) {
#pragma unroll
                for (int i = 0; i < 2; i++)
#pragma unroll
                    for (int j = 0; j < 4; j++)
#pragma unroll
                        for (int r = 0; r < 4; r++) {
                            int row = wrow0 + i * 16 + quad * 4 + r;
                            int key = k0 + j * 16 + lr;
                            float v = s[i][j][r] * sc2;
                            s[i][j][r] = (key > row) ? -INFINITY : v;
                        }
            } else {
#pragma unroll
                for (int i = 0; i < 2; i++)
#pragma unroll
                    for (int j = 0; j < 4; j++)
#pragma unroll
                        for (int r = 0; r < 4; r++) s[i][j][r] *= sc2;
            }
            // online softmax per row (i,r): max over j in-reg + 16-lane butterfly
            float al[2][4];
#pragma unroll
            for (int i = 0; i < 2; i++)
#pragma unroll
                for (int r = 0; r < 4; r++) {
                    float v = fmaxf(fmaxf(s[i][0][r], s[i][1][r]), fmaxf(s[i][2][r], s[i][3][r]));
                    v = fmaxf(v, __shfl_xor(v, 1));
                    v = fmaxf(v, __shfl_xor(v, 2));
                    v = fmaxf(v, __shfl_xor(v, 4));
                    v = fmaxf(v, __shfl_xor(v, 8));
                    float mn = fmaxf(m_i[i][r], v);
                    al[i][r] = exp2f(m_i[i][r] - mn);   // 0 on first visit
                    m_i[i][r] = mn;
                }
            // P = 2^(s-m), row sums, write to wave-local LDS (C-layout -> A-layout)
            float rs[2][4] = {{0.f, 0.f, 0.f, 0.f}, {0.f, 0.f, 0.f, 0.f}};
#pragma unroll
            for (int i = 0; i < 2; i++)
#pragma unroll
                for (int j = 0; j < 4; j++)
#pragma unroll
                    for (int r = 0; r < 4; r++) {
                        float p = exp2f(s[i][j][r] - m_i[i][r]);
                        rs[i][r] += p;
                        Ps[wid][i * 16 + quad * 4 + r][j * 16 + lr] = (f16)p;
                    }
#pragma unroll
            for (int i = 0; i < 2; i++)
#pragma unroll
                for (int r = 0; r < 4; r++) {
                    float v = rs[i][r];
                    v += __shfl_xor(v, 1);
                    v += __shfl_xor(v, 2);
                    v += __shfl_xor(v, 4);
                    v += __shfl_xor(v, 8);
                    l_i[i][r] = l_i[i][r] * al[i][r] + v;
                }
            // rescale O then O += P @ V  (Ps is wave-local: no __syncthreads needed)
#pragma unroll
            for (int i = 0; i < 2; i++)
#pragma unroll
                for (int j = 0; j < 4; j++)
#pragma unroll
                    for (int r = 0; r < 4; r++) o[i][j][r] *= al[i][r];
#pragma unroll
            for (int i = 0; i < 2; i++)
#pragma unroll
                for (int ks = 0; ks < 2; ks++) {
                    f16x8 ap = *(const f16x8*)&Ps[wid][i * 16 + lr][ks * 32 + lk];
#pragma unroll
                    for (int j = 0; j < 4; j++) {
                        f16x8 bv = *(const f16x8*)&Vt[j * 16 + lr][ks * 32 + lk];
                        o[i][j] = __builtin_amdgcn_mfma_f32_16x16x32_f16(ap, bv, o[i][j], 0, 0, 0);
                    }
                }
        }
    }

    // write ctx
#pragma unroll
    for (int i = 0; i < 2; i++)
#pragma unroll
        for (int r = 0; r < 4; r++) {
            float rl = 1.0f / l_i[i][r];
            int row = q0 + wid * 32 + i * 16 + quad * 4 + r;
#pragma unroll
            for (int j = 0; j < 4; j++) {
                int col = h * DHEAD + j * 16 + lr;
                ctx[(size_t)row * EMBED + col] = (f16)(o[i][j][r] * rl);
            }
        }
}

extern "C" void kernel_launch(void* const* d_in, const int* in_sizes, int n_in,
                              void* d_out, int out_size, void* d_ws, size_t ws_size,
                              hipStream_t stream) {
    const float* x     = (const float*)d_in[0];
    const float* Wq    = (const float*)d_in[1];
    const float* bq    = (const float*)d_in[2];
    const float* Wk    = (const float*)d_in[3];
    const float* bk    = (const float*)d_in[4];
    const float* Wv    = (const float*)d_in[5];
    const float* bv    = (const float*)d_in[6];
    const float* Wo    = (const float*)d_in[7];
    const float* bo    = (const float*)d_in[8];
    const float* ln1_g = (const float*)d_in[9];
    const float* ln1_b = (const float*)d_in[10];
    const float* ln2_g = (const float*)d_in[11];
    const float* ln2_b = (const float*)d_in[12];
    const float* W1    = (const float*)d_in[13];
    const float* b1    = (const float*)d_in[14];
    const float* W2    = (const float*)d_in[15];
    const float* b2    = (const float*)d_in[16];

    char* p = (char*)d_ws;
    auto alloc = [&](size_t bytes) -> void* {
        void* r = (void*)p;
        p += (bytes + 255) & ~(size_t)255;
        return r;
    };
    f16*   WqkvT = (f16*)alloc((size_t)CQKV * EMBED * 2);   // [2304][768]
    f16*   WoT   = (f16*)alloc((size_t)EMBED * EMBED * 2);  // [768][768]
    f16*   W1T   = (f16*)alloc((size_t)FFN_D * EMBED * 2);  // [3072][768]
    f16*   W2T   = (f16*)alloc((size_t)EMBED * FFN_D * 2);  // [768][3072]
    float* bqkv  = (float*)alloc((size_t)CQKV * 4);
    float* hf    = (float*)alloc((size_t)TSEQ * EMBED * 4);
    f16*   hh    = (f16*)alloc((size_t)TSEQ * EMBED * 2);
    f16*   qkv   = (f16*)alloc((size_t)TSEQ * CQKV * 2);
    f16*   vT    = (f16*)alloc((size_t)EMBED * TSEQ * 2);   // [h*64+d][t]
    f16*   ctx   = (f16*)alloc((size_t)TSEQ * EMBED * 2);
    float* x2    = (float*)alloc((size_t)TSEQ * EMBED * 4);
    float* h2f   = (float*)alloc((size_t)TSEQ * EMBED * 4);
    f16*   h2h   = (f16*)alloc((size_t)TSEQ * EMBED * 2);
    f16*   m1    = (f16*)alloc((size_t)TSEQ * FFN_D * 2);

    dim3 blk(256);
    tconv_kernel<<<dim3(EMBED / 32, EMBED / 32), blk, 0, stream>>>(Wq, WqkvT, EMBED, EMBED);
    tconv_kernel<<<dim3(EMBED / 32, EMBED / 32), blk, 0, stream>>>(Wk, WqkvT + (size_t)EMBED * EMBED, EMBED, EMBED);
    tconv_kernel<<<dim3(EMBED / 32, EMBED / 32), blk, 0, stream>>>(Wv, WqkvT + (size_t)2 * EMBED * EMBED, EMBED, EMBED);
    tconv_kernel<<<dim3(EMBED / 32, EMBED / 32), blk, 0, stream>>>(Wo, WoT, EMBED, EMBED);
    tconv_kernel<<<dim3(FFN_D / 32, EMBED / 32), blk, 0, stream>>>(W1, W1T, EMBED, FFN_D);
    tconv_kernel<<<dim3(EMBED / 32, FFN_D / 32), blk, 0, stream>>>(W2, W2T, FFN_D, EMBED);
    concat3_kernel<<<dim3(9), blk, 0, stream>>>(bq, bk, bv, bqkv);

    // LN1
    ln_kernel<<<dim3(TSEQ), blk, 0, stream>>>(x, ln1_g, ln1_b, hf, hh);
    // QKV fused GEMM
    gemm_kernel<0><<<dim3(CQKV / 128, TSEQ / 128), blk, 0, stream>>>(
        hh, WqkvT, bqkv, nullptr, nullptr, qkv, TSEQ, CQKV, EMBED);
    // V transpose for attention B-operand
    vtrans_kernel<<<dim3(TSEQ / 32, EMBED / 32), blk, 0, stream>>>(qkv, vT);
    // attention (128-row Q tiles, longest first)
    attn_kernel<<<dim3(NHEAD, TSEQ / 128), blk, 0, stream>>>(qkv, vT, ctx);
    // Wo GEMM + residual(h)
    gemm_kernel<1><<<dim3(EMBED / 128, TSEQ / 128), blk, 0, stream>>>(
        ctx, WoT, bo, hf, x2, nullptr, TSEQ, EMBED, EMBED);
    // LN2
    ln_kernel<<<dim3(TSEQ), blk, 0, stream>>>(x2, ln2_g, ln2_b, h2f, h2h);
    // FFN1 + gelu
    gemm_kernel<2><<<dim3(FFN_D / 128, TSEQ / 128), blk, 0, stream>>>(
        h2h, W1T, b1, nullptr, nullptr, m1, TSEQ, FFN_D, EMBED);
    // FFN2 + residual(h2) -> fp32 out
    gemm_kernel<1><<<dim3(EMBED / 128, TSEQ / 128), blk, 0, stream>>>(
        m1, W2T, b2, h2f, (float*)d_out, nullptr, TSEQ, EMBED, FFN_D);
}

// Round 3
// 462.207 us; speedup vs baseline: 1.1971x; 1.0922x over previous
//
#include <hip/hip_runtime.h>
#include <math.h>

#define EMBED 768
#define FFN_D 3072
#define TSEQ 4096
#define NHEAD 12
#define DHEAD 64
#define CQKV 2304   // 3*EMBED
#define NSPLIT 4

typedef _Float16 f16;
typedef __attribute__((ext_vector_type(8))) _Float16 f16x8;
typedef __attribute__((ext_vector_type(4))) float f32x4;

// ---------------- transpose + fp32->fp16 convert: W[din][dout] -> WT[dout][din]
__global__ __launch_bounds__(256) void tconv_kernel(const float* __restrict__ W,
                                                    f16* __restrict__ WT,
                                                    int din, int dout) {
    __shared__ float tile[32][33];
    const int j0 = blockIdx.x * 32;   // dout
    const int i0 = blockIdx.y * 32;   // din
    const int tx = threadIdx.x & 31;
    const int ty = threadIdx.x >> 5;  // 0..7
#pragma unroll
    for (int rr = ty; rr < 32; rr += 8)
        tile[rr][tx] = W[(size_t)(i0 + rr) * dout + j0 + tx];
    __syncthreads();
#pragma unroll
    for (int rr = ty; rr < 32; rr += 8)
        WT[(size_t)(j0 + rr) * din + i0 + tx] = (f16)tile[tx][rr];
}

// ---------------- f16 transpose of the V section of qkv -> vT[h*64+d][t]
__global__ __launch_bounds__(256) void vtrans_kernel(const f16* __restrict__ qkv,
                                                     f16* __restrict__ vT) {
    __shared__ f16 tile[32][34];
    const int t0 = blockIdx.x * 32;   // seq
    const int c0 = blockIdx.y * 32;   // channel 0..767
    const int tx = threadIdx.x & 31;
    const int ty = threadIdx.x >> 5;
#pragma unroll
    for (int rr = ty; rr < 32; rr += 8)
        tile[rr][tx] = qkv[(size_t)(t0 + rr) * CQKV + 2 * EMBED + c0 + tx];
    __syncthreads();
#pragma unroll
    for (int rr = ty; rr < 32; rr += 8)
        vT[(size_t)(c0 + rr) * TSEQ + t0 + tx] = tile[tx][rr];
}

// ---------------- concat 3 bias vectors of 768 into [2304]
__global__ void concat3_kernel(const float* __restrict__ a, const float* __restrict__ b,
                               const float* __restrict__ c, float* __restrict__ o) {
    int i = blockIdx.x * 256 + threadIdx.x;
    if (i < 768) o[i] = a[i];
    else if (i < 1536) o[i] = b[i - 768];
    else if (i < 2304) o[i] = c[i - 1536];
}

// ---------------- LayerNorm row kernel (768 wide), writes f32 + f16
__global__ __launch_bounds__(256) void ln_kernel(const float* __restrict__ x,
                                                 const float* __restrict__ g,
                                                 const float* __restrict__ b,
                                                 float* __restrict__ hf,
                                                 f16* __restrict__ hh) {
    const int row = blockIdx.x;
    const float* xr = x + (size_t)row * EMBED;
    const int t = threadIdx.x;
    float v0 = xr[t], v1 = xr[t + 256], v2 = xr[t + 512];
    float s = v0 + v1 + v2;
#pragma unroll
    for (int m = 1; m < 64; m <<= 1) s += __shfl_xor(s, m);
    __shared__ float red[4], red2[4];
    const int wid = t >> 6, lane = t & 63;
    if (lane == 0) red[wid] = s;
    __syncthreads();
    float mean = (red[0] + red[1] + red[2] + red[3]) * (1.0f / 768.0f);
    float d0 = v0 - mean, d1 = v1 - mean, d2 = v2 - mean;
    float ss = d0 * d0 + d1 * d1 + d2 * d2;
#pragma unroll
    for (int m = 1; m < 64; m <<= 1) ss += __shfl_xor(ss, m);
    if (lane == 0) red2[wid] = ss;
    __syncthreads();
    float inv = rsqrtf((red2[0] + red2[1] + red2[2] + red2[3]) * (1.0f / 768.0f) + 1e-5f);
    float o0 = d0 * inv * g[t] + b[t];
    float o1 = d1 * inv * g[t + 256] + b[t + 256];
    float o2 = d2 * inv * g[t + 512] + b[t + 512];
    size_t base = (size_t)row * EMBED;
    hf[base + t] = o0; hf[base + t + 256] = o1; hf[base + t + 512] = o2;
    hh[base + t] = (f16)o0; hh[base + t + 256] = (f16)o1; hh[base + t + 512] = (f16)o2;
}

// ---------------- GEMM: C[M][N] = A[M][K] * BT[N][K]^T + bias
// EPI 0: out fp16          EPI 1: out fp32 = acc+bias+res   EPI 2: out fp16 = gelu(acc+bias)
template <int EPI>
__global__ __launch_bounds__(256) void gemm_kernel(const f16* __restrict__ A,
                                                   const f16* __restrict__ BT,
                                                   const float* __restrict__ bias,
                                                   const float* __restrict__ res,
                                                   float* __restrict__ outf,
                                                   f16* __restrict__ outh,
                                                   int M, int N, int K) {
    __shared__ __align__(16) f16 As[128][40];
    __shared__ __align__(16) f16 Bs[128][40];
    const int t = threadIdx.x;
    const int m0 = blockIdx.y * 128;
    const int n0 = blockIdx.x * 128;
    const int sr = t >> 2;            // 0..63
    const int sc = (t & 3) * 8;       // 0,8,16,24
    const int wid = t >> 6;
    const int lane = t & 63;
    const int wm = (wid >> 1) * 64;
    const int wn = (wid & 1) * 64;
    const int lr = lane & 15;
    const int lk = (lane >> 4) * 8;

    f32x4 zero = {0.f, 0.f, 0.f, 0.f};
    f32x4 acc[4][4];
#pragma unroll
    for (int i = 0; i < 4; i++)
#pragma unroll
        for (int j = 0; j < 4; j++) acc[i][j] = zero;

    const f16* Ap = A + (size_t)(m0 + sr) * K + sc;
    const f16* Bp = BT + (size_t)(n0 + sr) * K + sc;

    for (int k0 = 0; k0 < K; k0 += 32) {
        __syncthreads();
        *(int4*)&As[sr][sc]      = *(const int4*)(Ap + k0);
        *(int4*)&As[sr + 64][sc] = *(const int4*)(Ap + (size_t)64 * K + k0);
        *(int4*)&Bs[sr][sc]      = *(const int4*)(Bp + k0);
        *(int4*)&Bs[sr + 64][sc] = *(const int4*)(Bp + (size_t)64 * K + k0);
        __syncthreads();
        f16x8 af[4], bf[4];
#pragma unroll
        for (int i = 0; i < 4; i++) af[i] = *(const f16x8*)&As[wm + i * 16 + lr][lk];
#pragma unroll
        for (int j = 0; j < 4; j++) bf[j] = *(const f16x8*)&Bs[wn + j * 16 + lr][lk];
#pragma unroll
        for (int i = 0; i < 4; i++)
#pragma unroll
            for (int j = 0; j < 4; j++)
                acc[i][j] = __builtin_amdgcn_mfma_f32_16x16x32_f16(af[i], bf[j], acc[i][j], 0, 0, 0);
    }

    const int q4 = (lane >> 4) * 4;
#pragma unroll
    for (int i = 0; i < 4; i++) {
        const int row = m0 + wm + i * 16 + q4;
#pragma unroll
        for (int j = 0; j < 4; j++) {
            const int col = n0 + wn + j * 16 + lr;
            const float bv = bias[col];
#pragma unroll
            for (int r = 0; r < 4; r++) {
                float v = acc[i][j][r] + bv;
                size_t idx = (size_t)(row + r) * N + col;
                if (EPI == 0) {
                    outh[idx] = (f16)v;
                } else if (EPI == 1) {
                    outf[idx] = v + res[idx];
                } else {
                    float gl = 0.5f * v * (1.0f + erff(v * 0.70710678118654752f));
                    outh[idx] = (f16)gl;
                }
            }
        }
    }
}

// ---------------- flash attention, 128-row Q tile, split-K partials
// Opart: [NSPLIT][TSEQ][768] fp32 unnormalized O.  ml: [NSPLIT][TSEQ][NHEAD] float2(m,l)
__global__ __launch_bounds__(256) void attn_kernel(const f16* __restrict__ qkv,
                                                   const f16* __restrict__ vT,
                                                   float* __restrict__ Opart,
                                                   float2* __restrict__ ml) {
    __shared__ __align__(16) f16 Qs[128][72];
    __shared__ __align__(16) f16 Ks[64][72];
    __shared__ __align__(16) f16 Vt[64][72];      // [d][key]
    __shared__ __align__(16) f16 Ps[4][32][72];   // per-wave P tile (wave-local, no barrier)
    const int h  = blockIdx.x;                    // 0..11
    const int qb = (gridDim.y - 1) - blockIdx.y;  // longest blocks dispatched first
    const int sp = blockIdx.z;
    const int q0 = qb * 128;
    const int t = threadIdx.x;
    const int wid = t >> 6;
    const int lane = t & 63;
    const int lr = lane & 15;
    const int quad = lane >> 4;
    const int lk = quad * 8;
    const int srow = t >> 3;        // 0..31
    const int scol = (t & 7) * 8;   // 0..56

    const int nkb = 2 * qb + 2;
    const int chunk = (nkb + NSPLIT - 1) / NSPLIT;
    const int kb0 = sp * chunk;
    const int kb1 = min(nkb, kb0 + chunk);

    // stage Q tile (128 rows x 64 d), coalesced 16B
    if (kb0 < kb1) {
        const f16* qbase = qkv + (size_t)q0 * CQKV + h * DHEAD;
#pragma unroll
        for (int p = 0; p < 4; p++) {
            int r = p * 32 + srow;
            *(int4*)&Qs[r][scol] = *(const int4*)(qbase + (size_t)r * CQKV + scol);
        }
    }

    float m_i[2][4], l_i[2][4];
    f32x4 zero = {0.f, 0.f, 0.f, 0.f};
    f32x4 o[2][4];
#pragma unroll
    for (int i = 0; i < 2; i++)
#pragma unroll
        for (int r = 0; r < 4; r++) { m_i[i][r] = -INFINITY; l_i[i][r] = 0.f; }
#pragma unroll
    for (int i = 0; i < 2; i++)
#pragma unroll
        for (int j = 0; j < 4; j++) o[i][j] = zero;

    const int wrow0 = q0 + wid * 32;       // first q-row of this wave
    const float sc2 = 0.125f * 1.4426950408889634f;   // 1/sqrt(64) * log2(e)

    // register prefetch of K/V tile kb0
    int4 kreg[2], vreg[2];
    const f16* kbase = qkv + EMBED + (size_t)h * DHEAD;
    const f16* vbase = vT + (size_t)h * DHEAD * TSEQ;
    if (kb0 < kb1) {
        const int k0 = kb0 * 64;
#pragma unroll
        for (int p = 0; p < 2; p++) {
            kreg[p] = *(const int4*)(kbase + (size_t)(k0 + p * 32 + srow) * CQKV + scol);
            vreg[p] = *(const int4*)(vbase + (size_t)(p * 32 + srow) * TSEQ + k0 + scol);
        }
    }

    for (int kb = kb0; kb < kb1; ++kb) {
        const int k0 = kb * 64;
        __syncthreads();   // prior iteration's reads of Ks/Vt done (also covers Q staging)
#pragma unroll
        for (int p = 0; p < 2; p++) {
            *(int4*)&Ks[p * 32 + srow][scol] = kreg[p];
            *(int4*)&Vt[p * 32 + srow][scol] = vreg[p];
        }
        __syncthreads();
        // issue next tile's loads (overlap with compute below)
        if (kb + 1 < kb1) {
            const int kn = (kb + 1) * 64;
#pragma unroll
            for (int p = 0; p < 2; p++) {
                kreg[p] = *(const int4*)(kbase + (size_t)(kn + p * 32 + srow) * CQKV + scol);
                vreg[p] = *(const int4*)(vbase + (size_t)(p * 32 + srow) * TSEQ + kn + scol);
            }
        }

        if (k0 <= wrow0 + 31) {   // wave-uniform: skip fully-masked tiles
            // S = Q K^T : 32 q-rows x 64 keys per wave
            f32x4 s[2][4];
#pragma unroll
            for (int i = 0; i < 2; i++)
#pragma unroll
                for (int j = 0; j < 4; j++) s[i][j] = zero;
#pragma unroll
            for (int i = 0; i < 2; i++)
#pragma unroll
                for (int ks = 0; ks < 2; ks++) {
                    f16x8 aq = *(const f16x8*)&Qs[wid * 32 + i * 16 + lr][ks * 32 + lk];
#pragma unroll
                    for (int j = 0; j < 4; j++) {
                        f16x8 bk = *(const f16x8*)&Ks[j * 16 + lr][ks * 32 + lk];
                        s[i][j] = __builtin_amdgcn_mfma_f32_16x16x32_f16(aq, bk, s[i][j], 0, 0, 0);
                    }
                }
            // scale into log2 domain (+ causal mask only on boundary tiles)
            if (k0 + 63 > wrow0) {
#pragma unroll
                for (int i = 0; i < 2; i++)
#pragma unroll
                    for (int j = 0; j < 4; j++)
#pragma unroll
                        for (int r = 0; r < 4; r++) {
                            int row = wrow0 + i * 16 + quad * 4 + r;
                            int key = k0 + j * 16 + lr;
                            float v = s[i][j][r] * sc2;
                            s[i][j][r] = (key > row) ? -INFINITY : v;
                        }
            } else {
#pragma unroll
                for (int i = 0; i < 2; i++)
#pragma unroll
                    for (int j = 0; j < 4; j++)
#pragma unroll
                        for (int r = 0; r < 4; r++) s[i][j][r] *= sc2;
            }
            // online softmax per row (i,r)
            float al[2][4];
#pragma unroll
            for (int i = 0; i < 2; i++)
#pragma unroll
                for (int r = 0; r < 4; r++) {
                    float v = fmaxf(fmaxf(s[i][0][r], s[i][1][r]), fmaxf(s[i][2][r], s[i][3][r]));
                    v = fmaxf(v, __shfl_xor(v, 1));
                    v = fmaxf(v, __shfl_xor(v, 2));
                    v = fmaxf(v, __shfl_xor(v, 4));
                    v = fmaxf(v, __shfl_xor(v, 8));
                    float mn = fmaxf(m_i[i][r], v);
                    al[i][r] = exp2f(m_i[i][r] - mn);   // 0 on first visit
                    m_i[i][r] = mn;
                }
            // P = 2^(s-m), row sums, write to wave-local LDS (C-layout -> A-layout)
            float rs[2][4] = {{0.f, 0.f, 0.f, 0.f}, {0.f, 0.f, 0.f, 0.f}};
#pragma unroll
            for (int i = 0; i < 2; i++)
#pragma unroll
                for (int j = 0; j < 4; j++)
#pragma unroll
                    for (int r = 0; r < 4; r++) {
                        float p = exp2f(s[i][j][r] - m_i[i][r]);
                        rs[i][r] += p;
                        Ps[wid][i * 16 + quad * 4 + r][j * 16 + lr] = (f16)p;
                    }
#pragma unroll
            for (int i = 0; i < 2; i++)
#pragma unroll
                for (int r = 0; r < 4; r++) {
                    float v = rs[i][r];
                    v += __shfl_xor(v, 1);
                    v += __shfl_xor(v, 2);
                    v += __shfl_xor(v, 4);
                    v += __shfl_xor(v, 8);
                    l_i[i][r] = l_i[i][r] * al[i][r] + v;
                }
            // rescale O then O += P @ V  (Ps is wave-local: no __syncthreads needed)
#pragma unroll
            for (int i = 0; i < 2; i++)
#pragma unroll
                for (int j = 0; j < 4; j++)
#pragma unroll
                    for (int r = 0; r < 4; r++) o[i][j][r] *= al[i][r];
#pragma unroll
            for (int i = 0; i < 2; i++)
#pragma unroll
                for (int ks = 0; ks < 2; ks++) {
                    f16x8 ap = *(const f16x8*)&Ps[wid][i * 16 + lr][ks * 32 + lk];
#pragma unroll
                    for (int j = 0; j < 4; j++) {
                        f16x8 bv = *(const f16x8*)&Vt[j * 16 + lr][ks * 32 + lk];
                        o[i][j] = __builtin_amdgcn_mfma_f32_16x16x32_f16(ap, bv, o[i][j], 0, 0, 0);
                    }
                }
        }
    }

    // write partials (unnormalized O + per-row m,l)
#pragma unroll
    for (int i = 0; i < 2; i++)
#pragma unroll
        for (int r = 0; r < 4; r++) {
            int row = q0 + wid * 32 + i * 16 + quad * 4 + r;
            float* orow = Opart + ((size_t)sp * TSEQ + row) * EMBED + h * DHEAD;
#pragma unroll
            for (int j = 0; j < 4; j++) orow[j * 16 + lr] = o[i][j][r];
            if (lr == 0)
                ml[((size_t)sp * TSEQ + row) * NHEAD + h] = make_float2(m_i[i][r], l_i[i][r]);
        }
}

// ---------------- merge split-K partials -> ctx f16
__global__ __launch_bounds__(256) void attn_merge_kernel(const float* __restrict__ Opart,
                                                         const float2* __restrict__ ml,
                                                         f16* __restrict__ ctx) {
    const int row = blockIdx.x;
    const int t = threadIdx.x;
    __shared__ float wgt[NSPLIT][NHEAD];
    if (t < NHEAD) {
        float m[NSPLIT], l[NSPLIT];
        float M = -INFINITY;
#pragma unroll
        for (int s = 0; s < NSPLIT; s++) {
            float2 v = ml[((size_t)s * TSEQ + row) * NHEAD + t];
            m[s] = v.x; l[s] = v.y;
            M = fmaxf(M, m[s]);
        }
        float L = 0.f;
        float w[NSPLIT];
#pragma unroll
        for (int s = 0; s < NSPLIT; s++) {
            w[s] = exp2f(m[s] - M);
            L += l[s] * w[s];
        }
        float rL = 1.0f / L;
#pragma unroll
        for (int s = 0; s < NSPLIT; s++) wgt[s][t] = w[s] * rL;
    }
    __syncthreads();
#pragma unroll
    for (int p = 0; p < 3; p++) {
        int c = t + p * 256;
        int h = c >> 6;
        float acc = 0.f;
#pragma unroll
        for (int s = 0; s < NSPLIT; s++)
            acc += wgt[s][h] * Opart[((size_t)s * TSEQ + row) * EMBED + c];
        ctx[(size_t)row * EMBED + c] = (f16)acc;
    }
}

extern "C" void kernel_launch(void* const* d_in, const int* in_sizes, int n_in,
                              void* d_out, int out_size, void* d_ws, size_t ws_size,
                              hipStream_t stream) {
    const float* x     = (const float*)d_in[0];
    const float* Wq    = (const float*)d_in[1];
    const float* bq    = (const float*)d_in[2];
    const float* Wk    = (const float*)d_in[3];
    const float* bk    = (const float*)d_in[4];
    const float* Wv    = (const float*)d_in[5];
    const float* bv    = (const float*)d_in[6];
    const float* Wo    = (const float*)d_in[7];
    const float* bo    = (const float*)d_in[8];
    const float* ln1_g = (const float*)d_in[9];
    const float* ln1_b = (const float*)d_in[10];
    const float* ln2_g = (const float*)d_in[11];
    const float* ln2_b = (const float*)d_in[12];
    const float* W1    = (const float*)d_in[13];
    const float* b1    = (const float*)d_in[14];
    const float* W2    = (const float*)d_in[15];
    const float* b2    = (const float*)d_in[16];

    char* p = (char*)d_ws;
    auto alloc = [&](size_t bytes) -> void* {
        void* r = (void*)p;
        p += (bytes + 255) & ~(size_t)255;
        return r;
    };
    f16*   WqkvT = (f16*)alloc((size_t)CQKV * EMBED * 2);   // [2304][768]
    f16*   WoT   = (f16*)alloc((size_t)EMBED * EMBED * 2);  // [768][768]
    f16*   W1T   = (f16*)alloc((size_t)FFN_D * EMBED * 2);  // [3072][768]
    f16*   W2T   = (f16*)alloc((size_t)EMBED * FFN_D * 2);  // [768][3072]
    float* bqkv  = (float*)alloc((size_t)CQKV * 4);
    float* hf    = (float*)alloc((size_t)TSEQ * EMBED * 4);
    f16*   hh    = (f16*)alloc((size_t)TSEQ * EMBED * 2);
    f16*   qkv   = (f16*)alloc((size_t)TSEQ * CQKV * 2);
    f16*   vT    = (f16*)alloc((size_t)EMBED * TSEQ * 2);   // [h*64+d][t]
    f16*   ctx   = (f16*)alloc((size_t)TSEQ * EMBED * 2);
    float* x2    = (float*)alloc((size_t)TSEQ * EMBED * 4);
    float* h2f   = (float*)alloc((size_t)TSEQ * EMBED * 4);
    f16*   h2h   = (f16*)alloc((size_t)TSEQ * EMBED * 2);
    f16*   m1    = (f16*)alloc((size_t)TSEQ * FFN_D * 2);

    // split-K attention partials ALIAS the post-attention buffers (x2..m1 span
    // 56.7 MB >= 50.3+1.6 MB; attention+merge complete before x2 is written)
    float*  Opart = x2;                                        // [NSPLIT][TSEQ][768] f32
    float2* mlbuf = (float2*)(x2 + (size_t)NSPLIT * TSEQ * EMBED);

    dim3 blk(256);
    tconv_kernel<<<dim3(EMBED / 32, EMBED / 32), blk, 0, stream>>>(Wq, WqkvT, EMBED, EMBED);
    tconv_kernel<<<dim3(EMBED / 32, EMBED / 32), blk, 0, stream>>>(Wk, WqkvT + (size_t)EMBED * EMBED, EMBED, EMBED);
    tconv_kernel<<<dim3(EMBED / 32, EMBED / 32), blk, 0, stream>>>(Wv, WqkvT + (size_t)2 * EMBED * EMBED, EMBED, EMBED);
    tconv_kernel<<<dim3(EMBED / 32, EMBED / 32), blk, 0, stream>>>(Wo, WoT, EMBED, EMBED);
    tconv_kernel<<<dim3(FFN_D / 32, EMBED / 32), blk, 0, stream>>>(W1, W1T, EMBED, FFN_D);
    tconv_kernel<<<dim3(EMBED / 32, FFN_D / 32), blk, 0, stream>>>(W2, W2T, FFN_D, EMBED);
    concat3_kernel<<<dim3(9), blk, 0, stream>>>(bq, bk, bv, bqkv);

    // LN1
    ln_kernel<<<dim3(TSEQ), blk, 0, stream>>>(x, ln1_g, ln1_b, hf, hh);
    // QKV fused GEMM
    gemm_kernel<0><<<dim3(CQKV / 128, TSEQ / 128), blk, 0, stream>>>(
        hh, WqkvT, bqkv, nullptr, nullptr, qkv, TSEQ, CQKV, EMBED);
    // V transpose for attention B-operand
    vtrans_kernel<<<dim3(TSEQ / 32, EMBED / 32), blk, 0, stream>>>(qkv, vT);
    // attention split-K partials + merge
    attn_kernel<<<dim3(NHEAD, TSEQ / 128, NSPLIT), blk, 0, stream>>>(qkv, vT, Opart, mlbuf);
    attn_merge_kernel<<<dim3(TSEQ), blk, 0, stream>>>(Opart, mlbuf, ctx);
    // Wo GEMM + residual(h)  (overwrites the Opart alias region - partials are dead)
    gemm_kernel<1><<<dim3(EMBED / 128, TSEQ / 128), blk, 0, stream>>>(
        ctx, WoT, bo, hf, x2, nullptr, TSEQ, EMBED, EMBED);
    // LN2
    ln_kernel<<<dim3(TSEQ), blk, 0, stream>>>(x2, ln2_g, ln2_b, h2f, h2h);
    // FFN1 + gelu
    gemm_kernel<2><<<dim3(FFN_D / 128, TSEQ / 128), blk, 0, stream>>>(
        h2h, W1T, b1, nullptr, nullptr, m1, TSEQ, FFN_D, EMBED);
    // FFN2 + residual(h2) -> fp32 out
    gemm_kernel<1><<<dim3(EMBED / 128, TSEQ / 128), blk, 0, stream>>>(
        m1, W2T, b2, h2f, (float*)d_out, nullptr, TSEQ, EMBED, FFN_D);
}